// Round 14
// baseline (204.952 us; speedup 1.0000x reference)
//
#include <hip/hip_runtime.h>
#include <hip/hip_fp16.h>

#define EMB_D 64
#define SPAN 128     // nodes per group (group = dst>>7, local = dst&127)
#define SPAN_SH 7
#define MAXG 1024    // max groups for LDS arrays
#define NCHUNK2 1024 // edge chunks for partition (4 blocks/CU)
#define CHMAX 2048   // max edges per chunk (16 KB recs)
#define TILE 4096    // gather tile (records)
#define CAST_BLOCKS 256

// ===========================================================================
// Tier A14: A13 + partition occupancy fix (NCHUNK2 512 -> 1024).
//   A1 : fused fp16 cast (float4) + per-chunk group hist -> cntT[G][1024]
//   RS : rowsum: G blocks sum cntT rows -> hist[G]
//   SC : one block scans G bins -> offsets[G+1] + cursors[G]
//   PR : partition_res: LDS counting sort; counts from cntT, base via one
//        atomicAdd(&cursors[g], cnt); XCD-contiguous chunk remap.
//        1024 blocks x 512 thr, 24.5 KB LDS -> 4 blocks/CU (was 2) --
//        R13 showed it latency-bound at 31% occupancy, 0.8 TB/s.
//   GF : gather_fused = R6 proven (lrec, 16-lane crews, 2x2-deep substreams).
// Tier C : atomic scatter fallback.
// Ledger: R4 LDS-atomic accum ~100x slow. R6 gather local-opt ~46-55us,
// L2-miss-bound 147MB@~3.3TB/s; slice phasing (R7-R9) cut FETCH to 43MB
// but shattered the walk -> abandoned. R10: gather occupancy not limiter.
// R12/R13: arrival-order stream + cursor atomics OK; partition is
// latency-bound, needs waves not bandwidth.
// ===========================================================================

__device__ __forceinline__ float h15_to_float(unsigned int bits) {
    return __half2float(__ushort_as_half((unsigned short)bits));
}

__device__ __forceinline__ uint4 rowld(const char* base, unsigned int pk,
                                       unsigned int qlo) {
    return *reinterpret_cast<const uint4*>(base + ((pk >> 15) * 128u + qlo));
}

__device__ __forceinline__ void fma8(float4& a, float4& b, uint4 r, float wt) {
    float2 x01 = __half22float2(*reinterpret_cast<__half2*>(&r.x));
    float2 x23 = __half22float2(*reinterpret_cast<__half2*>(&r.y));
    float2 x45 = __half22float2(*reinterpret_cast<__half2*>(&r.z));
    float2 x67 = __half22float2(*reinterpret_cast<__half2*>(&r.w));
    a.x = fmaf(x01.x, wt, a.x); a.y = fmaf(x01.y, wt, a.y);
    a.z = fmaf(x23.x, wt, a.z); a.w = fmaf(x23.y, wt, a.w);
    b.x = fmaf(x45.x, wt, b.x); b.y = fmaf(x45.y, wt, b.y);
    b.z = fmaf(x67.x, wt, b.z); b.w = fmaf(x67.y, wt, b.w);
}

// --- A1: fused cast (float4) + per-chunk group histogram ------------------
__global__ void a1_cast_hist(const float4* __restrict__ embin,
                             uint2* __restrict__ emb16, int n4,
                             const int* __restrict__ dst,
                             int* __restrict__ cntT,   // [G][NCHUNK2]
                             int E, int G, int chunk) {
    if (blockIdx.x < CAST_BLOCKS) {
        int i = blockIdx.x * blockDim.x + threadIdx.x;
        int st = CAST_BLOCKS * blockDim.x;
        for (; i < n4; i += st) {
            float4 v = embin[i];
            __half2 h0 = __float22half2_rn(make_float2(v.x, v.y));
            __half2 h1 = __float22half2_rn(make_float2(v.z, v.w));
            emb16[i] = make_uint2(*reinterpret_cast<unsigned int*>(&h0),
                                  *reinterpret_cast<unsigned int*>(&h1));
        }
    } else {
        __shared__ int bins[MAXG];
        int hb = blockIdx.x - CAST_BLOCKS;
        for (int g = threadIdx.x; g < G; g += blockDim.x) bins[g] = 0;
        __syncthreads();
        int beg = hb * chunk;
        int end = min(beg + chunk, E);
        for (int i = beg + threadIdx.x; i < end; i += blockDim.x)
            atomicAdd(&bins[dst[i] >> SPAN_SH], 1);
        __syncthreads();
        for (int g = threadIdx.x; g < G; g += blockDim.x)
            cntT[g * NCHUNK2 + hb] = bins[g];
    }
}

// --- RS: per-group row sum of cntT -> hist --------------------------------
__global__ void rowsum_kernel(const int* __restrict__ cntT,
                              int* __restrict__ hist, int G) {
    __shared__ int wsum[4];
    const int g = blockIdx.x;
    const int tid = threadIdx.x, lane = tid & 63, wid = tid >> 6;
    const int* row = cntT + (size_t)g * NCHUNK2;
    int s = row[tid] + row[tid + 256] + row[tid + 512] + row[tid + 768];
    #pragma unroll
    for (int off = 32; off > 0; off >>= 1)
        s += __shfl_xor(s, off, 64);
    if (lane == 0) wsum[wid] = s;
    __syncthreads();
    if (tid == 0)
        hist[g] = wsum[0] + wsum[1] + wsum[2] + wsum[3];
}

// --- SC: single-block exclusive scan of G (<=1024) bins -------------------
__global__ void f2_scan_small(const int* __restrict__ hist,
                              int* __restrict__ offsets,
                              int* __restrict__ cursors, int G) {
    __shared__ int wsum[16];
    __shared__ int wpre[16];
    const int tid = threadIdx.x, lane = tid & 63, wid = tid >> 6;
    int v = (tid < G) ? hist[tid] : 0;
    int x = v;
    #pragma unroll
    for (int off = 1; off < 64; off <<= 1) {
        int t = __shfl_up(x, off, 64);
        if (lane >= off) x += t;
    }
    if (lane == 63) wsum[wid] = x;
    __syncthreads();
    if (wid == 0) {
        int s = (lane < 16) ? wsum[lane] : 0;
        #pragma unroll
        for (int off = 1; off < 16; off <<= 1) {
            int t = __shfl_up(s, off, 64);
            if (lane >= off) s += t;
        }
        if (lane < 16) wpre[lane] = s;
    }
    __syncthreads();
    int excl = ((wid > 0) ? wpre[wid - 1] : 0) + (x - v);
    if (tid < G) { offsets[tid] = excl; cursors[tid] = excl; }
    if (tid == 0) offsets[G] = wpre[15];   // grand total = E
}

// --- PR: partition with cntT counts + atomic reservation ------------------
__global__ __launch_bounds__(512) void partition_res(
        const int* __restrict__ src,
        const int* __restrict__ dst,
        const float* __restrict__ w,
        const int* __restrict__ cntT,    // [G][NCHUNK2]
        int* __restrict__ cursors,       // [G] init = offsets[g]
        uint2* __restrict__ stream8,     // [E]
        int E, int G, int chunk) {
    __shared__ uint2 recs[CHMAX];        // 16 KB
    __shared__ int cur[MAXG];            // 4 KB
    __shared__ int delta[MAXG];          // 4 KB
    __shared__ int wtot[8];

    const int tid = threadIdx.x, lane = tid & 63, wv = tid >> 6;
    // XCD-contiguous remap: block b (XCD b%8) takes chunk (b%8)*128 + b/8,
    // so adjacent output runs land on the SAME XCD (write combining).
    const int b = blockIdx.x;
    const int c = (b & 7) * (NCHUNK2 >> 3) + (b >> 3);
    const int beg = c * chunk;
    const int end = min(beg + chunk, E);
    const int n = end - beg;

    // local counts from cntT; in-block scan -> local starts; atomic base
    const int K = (G + 511) >> 9;        // <= 2 (G <= MAXG)
    int vals[2];
    int acc = 0;
    #pragma unroll
    for (int k = 0; k < 2; ++k) {
        int g = tid * K + k;
        int cc = (k < K && g < G) ? cntT[g * NCHUNK2 + c] : 0;
        vals[k] = cc;
        acc += cc;
    }
    int x = acc;
    #pragma unroll
    for (int off = 1; off < 64; off <<= 1) {
        int t = __shfl_up(x, off, 64);
        if (lane >= off) x += t;
    }
    if (lane == 63) wtot[wv] = x;
    __syncthreads();
    int woff = 0;
    #pragma unroll
    for (int k2 = 0; k2 < 8; ++k2)
        woff += (k2 < wv) ? wtot[k2] : 0;
    int run = woff + x - acc;            // exclusive local start
    #pragma unroll
    for (int k = 0; k < 2; ++k) {
        int g = tid * K + k;
        if (k < K && g < G) {
            int cc = vals[k];
            cur[g] = run;                // own entries only: no race
            if (cc > 0)
                delta[g] = atomicAdd(&cursors[g], cc) - run;
            run += cc;
        }
    }
    __syncthreads();

    // LDS scatter, group-sorted (single dst/src/w pass; edges L3-hot)
    for (int i = beg + tid; i < end; i += 512) {
        int d = dst[i];
        unsigned int wb = __half_as_ushort(__float2half_rn(w[i]));
        unsigned int pk = ((unsigned int)src[i] << 15) | (wb & 0x7FFFu);
        int g = d >> SPAN_SH;
        int j = atomicAdd(&cur[g], 1);
        recs[j] = make_uint2(pk, (unsigned int)(d & (SPAN - 1)) |
                                 ((unsigned int)g << SPAN_SH));
    }
    __syncthreads();

    // linear coalesced drain
    for (int j = tid; j < n; j += 512) {
        uint2 r = recs[j];
        int g = (int)(r.y >> SPAN_SH);
        stream8[delta[g] + j] = make_uint2(r.x, r.y & (SPAN - 1u));
    }
}

// --- GF: fused per-group CSR + register gather + normalize (R6 proven) ----
__global__ __launch_bounds__(512) void gather_fused(
        const char* __restrict__ emb16b,      // row v at byte v*128
        const uint2* __restrict__ stream8,    // [E] {pk, dl}
        const int* __restrict__ offsets,      // [G+1]
        float* __restrict__ out, int N) {
    __shared__ uint2 lrec[TILE];              // 32 KB
    __shared__ unsigned int srt[TILE];        // 16 KB
    __shared__ int hcnt[SPAN];
    __shared__ int nstart[SPAN];
    __shared__ int cur[SPAN];
    __shared__ int wtot[2];

    const int g = blockIdx.x;
    const int tid = threadIdx.x;
    const int lane = tid & 63, wv = tid >> 6;
    const int base = offsets[g];
    const int endE = offsets[g + 1];
    const int crew = tid >> 4;                   // 0..31
    const int ql = tid & 15;
    const int sub = ql >> 3;                     // substream 0/1
    const int sl = ql & 7;                       // 16B segment of row
    const unsigned qlo = (unsigned)(sl << 4);

    float4 accA[4], accB[4];                  // dims sl*8+0..3 / +4..7
    #pragma unroll
    for (int ni = 0; ni < 4; ++ni) {
        accA[ni] = make_float4(0.f, 0.f, 0.f, 0.f);
        accB[ni] = make_float4(0.f, 0.f, 0.f, 0.f);
    }

    for (int tb = base; tb < endE; tb += TILE) {
        const int n = min(TILE, endE - tb);
        if (tid < SPAN) hcnt[tid] = 0;
        __syncthreads();
        for (int j = tid; j < n; j += 512) {
            uint2 r = stream8[tb + j];
            lrec[j] = r;
            atomicAdd(&hcnt[r.y], 1);
        }
        __syncthreads();
        int v = (tid < SPAN) ? hcnt[tid] : 0;
        int x = v;
        #pragma unroll
        for (int off = 1; off < 64; off <<= 1) {
            int t = __shfl_up(x, off, 64);
            if (lane >= off) x += t;
        }
        if (wv < 2 && lane == 63) wtot[wv] = x;
        __syncthreads();
        if (tid < SPAN) {
            int excl = x - v + ((wv == 1) ? wtot[0] : 0);
            nstart[tid] = excl;
            cur[tid] = excl;
        }
        __syncthreads();
        for (int j = tid; j < n; j += 512) {
            uint2 r = lrec[j];
            int slot = atomicAdd(&cur[r.y], 1);
            srt[slot] = r.x;
        }
        __syncthreads();
        #pragma unroll
        for (int ni = 0; ni < 4; ++ni) {
            int nd = crew + (ni << 5);
            int s = nstart[nd];
            int e = cur[nd];
            float4 aA = accA[ni];
            float4 aB = accB[ni];
            int k0 = s + sub;
            unsigned int pk0 = (k0 < e) ? srt[k0] : 0u;
            uint4 r0 = rowld(emb16b, pk0, qlo);
            for (int k = k0; k < e; k += 2) {
                int k1 = k + 2;
                unsigned int pk1 = (k1 < e) ? srt[k1] : 0u;
                uint4 r1 = rowld(emb16b, pk1, qlo);   // next in flight
                fma8(aA, aB, r0, h15_to_float(pk0 & 0x7FFFu));
                pk0 = pk1; r0 = r1;
            }
            accA[ni] = aA;
            accB[ni] = aB;
        }
        __syncthreads();
    }

    // merge substreams, normalize, write
    #pragma unroll
    for (int ni = 0; ni < 4; ++ni) {
        accA[ni].x += __shfl_xor(accA[ni].x, 8, 64);
        accA[ni].y += __shfl_xor(accA[ni].y, 8, 64);
        accA[ni].z += __shfl_xor(accA[ni].z, 8, 64);
        accA[ni].w += __shfl_xor(accA[ni].w, 8, 64);
        accB[ni].x += __shfl_xor(accB[ni].x, 8, 64);
        accB[ni].y += __shfl_xor(accB[ni].y, 8, 64);
        accB[ni].z += __shfl_xor(accB[ni].z, 8, 64);
        accB[ni].w += __shfl_xor(accB[ni].w, 8, 64);
        int node = g * SPAN + crew + (ni << 5);
        float4 aA = accA[ni];
        float4 aB = accB[ni];
        float ss = aA.x * aA.x + aA.y * aA.y + aA.z * aA.z + aA.w * aA.w
                 + aB.x * aB.x + aB.y * aB.y + aB.z * aB.z + aB.w * aB.w;
        ss += __shfl_xor(ss, 1, 64);
        ss += __shfl_xor(ss, 2, 64);
        ss += __shfl_xor(ss, 4, 64);
        float scale = 1.0f / fmaxf(sqrtf(ss), 1e-12f);
        if (node < N) {
            float4 a = sub ? aB : aA;
            float4 o = make_float4(a.x * scale, a.y * scale,
                                   a.z * scale, a.w * scale);
            *reinterpret_cast<float4*>(out + (size_t)node * EMB_D
                                       + (sl << 3) + (sub << 2)) = o;
        }
    }
}

// ===========================================================================
// Tier C: atomic scatter fallback.
// ===========================================================================
__global__ void lightgcn_scatter(const float* __restrict__ emb,
                                 const float* __restrict__ w,
                                 const int* __restrict__ src,
                                 const int* __restrict__ dst,
                                 float* __restrict__ h, int E) {
    long long t = (long long)blockIdx.x * blockDim.x + threadIdx.x;
    int e = (int)(t >> 4);
    int d = (int)(t & 15) << 2;
    if (e >= E) return;
    int s = src[e]; int v = dst[e]; float wt = w[e];
    const float4 m = *reinterpret_cast<const float4*>(emb + (size_t)s * EMB_D + d);
    float* o = h + (size_t)v * EMB_D + d;
    unsafeAtomicAdd(o + 0, m.x * wt);
    unsafeAtomicAdd(o + 1, m.y * wt);
    unsafeAtomicAdd(o + 2, m.z * wt);
    unsafeAtomicAdd(o + 3, m.w * wt);
}

__global__ void lightgcn_normalize(float* __restrict__ h, int N) {
    int row = blockIdx.x * (blockDim.x >> 6) + (threadIdx.x >> 6);
    int lane = threadIdx.x & 63;
    if (row >= N) return;
    float x = h[(size_t)row * EMB_D + lane];
    float ss = x * x;
    #pragma unroll
    for (int off = 32; off > 0; off >>= 1)
        ss += __shfl_xor(ss, off, 64);
    h[(size_t)row * EMB_D + lane] = x / fmaxf(sqrtf(ss), 1e-12f);
}

extern "C" void kernel_launch(void* const* d_in, const int* in_sizes, int n_in,
                              void* d_out, int out_size, void* d_ws, size_t ws_size,
                              hipStream_t stream) {
    const float* emb = (const float*)d_in[0];   // [N, 64] fp32
    const float* w   = (const float*)d_in[1];   // [E] fp32
    const int*   src = (const int*)d_in[2];     // [E] int32
    const int*   dst = (const int*)d_in[3];     // [E] int32
    float* out = (float*)d_out;

    const int N = in_sizes[0] / EMB_D;
    const int E = in_sizes[1];
    const int block = 256;
    const int G = (N + SPAN - 1) / SPAN;
    const int chunk = (E + NCHUNK2 - 1) / NCHUNK2;

    // ---- workspace: cntT[G*NCHUNK2] | hist[G] | offsets[G+1] | cursors[G]
    //      | pad | stream8[E] uint2 | pad | emb16  (~27.5 MB) ----
    size_t ints = (size_t)G * NCHUNK2 + 3 * (size_t)G + 1;
    size_t strOff = (ints * sizeof(int) + 15) & ~(size_t)15;
    size_t embOff = (strOff + (size_t)E * sizeof(uint2) + 15) & ~(size_t)15;
    size_t needed = embOff + (size_t)N * EMB_D * sizeof(__half);

    if (ws_size >= needed && G <= MAXG && chunk <= CHMAX &&
        E < (1 << 28) && N < (1 << 17)) {
        int* cntT    = (int*)d_ws;               // G*NCHUNK2
        int* hist    = cntT + (size_t)G * NCHUNK2;  // G
        int* offsets = hist + G;                 // G+1
        int* cursors = offsets + G + 1;          // G
        uint2* stream8 = (uint2*)((char*)d_ws + strOff);   // E
        uint2* emb16 = (uint2*)((char*)d_ws + embOff);

        int n4 = N * (EMB_D / 4);

        a1_cast_hist<<<CAST_BLOCKS + NCHUNK2, block, 0, stream>>>(
            (const float4*)emb, emb16, n4, dst, cntT, E, G, chunk);

        rowsum_kernel<<<G, 256, 0, stream>>>(cntT, hist, G);
        f2_scan_small<<<1, 1024, 0, stream>>>(hist, offsets, cursors, G);

        partition_res<<<NCHUNK2, 512, 0, stream>>>(src, dst, w, cntT, cursors,
                                                   stream8, E, G, chunk);

        gather_fused<<<G, 512, 0, stream>>>((const char*)emb16, stream8,
                                            offsets, out, N);
    } else {
        hipMemsetAsync(d_out, 0, (size_t)out_size * sizeof(float), stream);
        long long total = (long long)E * 16;
        int grid = (int)((total + block - 1) / block);
        lightgcn_scatter<<<grid, block, 0, stream>>>(emb, w, src, dst, out, E);
        int gridN = (N + 3) / 4;
        lightgcn_normalize<<<gridN, 256, 0, stream>>>(out, N);
    }
}

// Round 15
// 177.352 us; speedup vs baseline: 1.1556x; 1.1556x over previous
//
#include <hip/hip_runtime.h>
#include <hip/hip_fp16.h>

#define EMB_D 64
#define SPAN 128     // nodes per group (group = dst>>7, local = dst&127)
#define SPAN_SH 7
#define MAXG 1024    // max groups for LDS arrays
#define NCHUNK2 512  // edge chunks for partition (proven optimum, R13/R14)
#define CHMAX 4096   // max edges per chunk (32 KB recs)
#define TILE 4096    // gather tile (records)
#define CAST_BLOCKS 256

// ===========================================================================
// Tier A13 (FINAL): hybrid front-end — cnt matrix + atomic reservation.
//   A1 : fused fp16 cast (float4) + per-chunk group hist -> cntT[G][512]
//   RS : rowsum: G blocks sum cntT rows -> hist[G]
//   SC : one block scans G bins -> offsets[G+1] + cursors[G]
//   PR : partition_res: LDS counting sort; counts from cntT, base via one
//        atomicAdd(&cursors[g], cnt); XCD-contiguous chunk remap.
//   GF : gather_fused = R6 proven (lrec, 16-lane crews, 2x2-deep substreams
//        = 16 rows/wave in flight), fused L2-normalize.
// Tier C : atomic scatter fallback.
// Ledger (14 rounds): R4 LDS-atomic accumulate ~100x too slow. R6 gather
// local-opt ~46-55us, fetch-bound at random-gather plateau (147MB@3.3TB/s,
// L2-capacity). R7-R9: slice phasing cuts FETCH to 43MB but shatters walk
// MLP (short lists) -> 3 attempts all regressed; abandoned. R10: gather
// occupancy not the limiter; drain is write-combining-bound (run length).
// R12/R13: arrival-order stream + cursor atomics sound; partition's own
// hist pass costlier than scans. R14: NCHUNK2 1024 regressed (runs 3.5 ->
// write amp 33MB + 2x cursor contention) -> partition floor is 512 chunks.
// This config = measured session best (175.4-175.6 us).
// ===========================================================================

__device__ __forceinline__ float h15_to_float(unsigned int bits) {
    return __half2float(__ushort_as_half((unsigned short)bits));
}

__device__ __forceinline__ uint4 rowld(const char* base, unsigned int pk,
                                       unsigned int qlo) {
    return *reinterpret_cast<const uint4*>(base + ((pk >> 15) * 128u + qlo));
}

__device__ __forceinline__ void fma8(float4& a, float4& b, uint4 r, float wt) {
    float2 x01 = __half22float2(*reinterpret_cast<__half2*>(&r.x));
    float2 x23 = __half22float2(*reinterpret_cast<__half2*>(&r.y));
    float2 x45 = __half22float2(*reinterpret_cast<__half2*>(&r.z));
    float2 x67 = __half22float2(*reinterpret_cast<__half2*>(&r.w));
    a.x = fmaf(x01.x, wt, a.x); a.y = fmaf(x01.y, wt, a.y);
    a.z = fmaf(x23.x, wt, a.z); a.w = fmaf(x23.y, wt, a.w);
    b.x = fmaf(x45.x, wt, b.x); b.y = fmaf(x45.y, wt, b.y);
    b.z = fmaf(x67.x, wt, b.z); b.w = fmaf(x67.y, wt, b.w);
}

// --- A1: fused cast (float4) + per-chunk group histogram ------------------
__global__ void a1_cast_hist(const float4* __restrict__ embin,
                             uint2* __restrict__ emb16, int n4,
                             const int* __restrict__ dst,
                             int* __restrict__ cntT,   // [G][NCHUNK2]
                             int E, int G, int chunk) {
    if (blockIdx.x < CAST_BLOCKS) {
        int i = blockIdx.x * blockDim.x + threadIdx.x;
        int st = CAST_BLOCKS * blockDim.x;
        for (; i < n4; i += st) {
            float4 v = embin[i];
            __half2 h0 = __float22half2_rn(make_float2(v.x, v.y));
            __half2 h1 = __float22half2_rn(make_float2(v.z, v.w));
            emb16[i] = make_uint2(*reinterpret_cast<unsigned int*>(&h0),
                                  *reinterpret_cast<unsigned int*>(&h1));
        }
    } else {
        __shared__ int bins[MAXG];
        int hb = blockIdx.x - CAST_BLOCKS;
        for (int g = threadIdx.x; g < G; g += blockDim.x) bins[g] = 0;
        __syncthreads();
        int beg = hb * chunk;
        int end = min(beg + chunk, E);
        for (int i = beg + threadIdx.x; i < end; i += blockDim.x)
            atomicAdd(&bins[dst[i] >> SPAN_SH], 1);
        __syncthreads();
        for (int g = threadIdx.x; g < G; g += blockDim.x)
            cntT[g * NCHUNK2 + hb] = bins[g];
    }
}

// --- RS: per-group row sum of cntT -> hist --------------------------------
__global__ void rowsum_kernel(const int* __restrict__ cntT,
                              int* __restrict__ hist, int G) {
    __shared__ int wsum[4];
    const int g = blockIdx.x;
    const int tid = threadIdx.x, lane = tid & 63, wid = tid >> 6;
    int s = cntT[g * NCHUNK2 + tid] + cntT[g * NCHUNK2 + tid + 256];
    #pragma unroll
    for (int off = 32; off > 0; off >>= 1)
        s += __shfl_xor(s, off, 64);
    if (lane == 0) wsum[wid] = s;
    __syncthreads();
    if (tid == 0)
        hist[g] = wsum[0] + wsum[1] + wsum[2] + wsum[3];
}

// --- SC: single-block exclusive scan of G (<=1024) bins -------------------
__global__ void f2_scan_small(const int* __restrict__ hist,
                              int* __restrict__ offsets,
                              int* __restrict__ cursors, int G) {
    __shared__ int wsum[16];
    __shared__ int wpre[16];
    const int tid = threadIdx.x, lane = tid & 63, wid = tid >> 6;
    int v = (tid < G) ? hist[tid] : 0;
    int x = v;
    #pragma unroll
    for (int off = 1; off < 64; off <<= 1) {
        int t = __shfl_up(x, off, 64);
        if (lane >= off) x += t;
    }
    if (lane == 63) wsum[wid] = x;
    __syncthreads();
    if (wid == 0) {
        int s = (lane < 16) ? wsum[lane] : 0;
        #pragma unroll
        for (int off = 1; off < 16; off <<= 1) {
            int t = __shfl_up(s, off, 64);
            if (lane >= off) s += t;
        }
        if (lane < 16) wpre[lane] = s;
    }
    __syncthreads();
    int excl = ((wid > 0) ? wpre[wid - 1] : 0) + (x - v);
    if (tid < G) { offsets[tid] = excl; cursors[tid] = excl; }
    if (tid == 0) offsets[G] = wpre[15];   // grand total = E
}

// --- PR: partition with cntT counts + atomic reservation ------------------
__global__ __launch_bounds__(512) void partition_res(
        const int* __restrict__ src,
        const int* __restrict__ dst,
        const float* __restrict__ w,
        const int* __restrict__ cntT,    // [G][NCHUNK2]
        int* __restrict__ cursors,       // [G] init = offsets[g]
        uint2* __restrict__ stream8,     // [E]
        int E, int G, int chunk) {
    __shared__ uint2 recs[CHMAX];        // 32 KB
    __shared__ int cur[MAXG];            // 4 KB
    __shared__ int delta[MAXG];          // 4 KB
    __shared__ int wtot[8];

    const int tid = threadIdx.x, lane = tid & 63, wv = tid >> 6;
    // XCD-contiguous remap: block b (XCD b%8) takes chunk (b%8)*64 + b/8,
    // so adjacent output runs land on the SAME XCD (write combining).
    const int b = blockIdx.x;
    const int c = (b & 7) * (NCHUNK2 >> 3) + (b >> 3);
    const int beg = c * chunk;
    const int end = min(beg + chunk, E);
    const int n = end - beg;

    // local counts from cntT; in-block scan -> local starts; atomic base
    const int K = (G + 511) >> 9;        // <= 2 (G <= MAXG)
    int vals[2];
    int acc = 0;
    #pragma unroll
    for (int k = 0; k < 2; ++k) {
        int g = tid * K + k;
        int cc = (k < K && g < G) ? cntT[g * NCHUNK2 + c] : 0;
        vals[k] = cc;
        acc += cc;
    }
    int x = acc;
    #pragma unroll
    for (int off = 1; off < 64; off <<= 1) {
        int t = __shfl_up(x, off, 64);
        if (lane >= off) x += t;
    }
    if (lane == 63) wtot[wv] = x;
    __syncthreads();
    int woff = 0;
    #pragma unroll
    for (int k2 = 0; k2 < 8; ++k2)
        woff += (k2 < wv) ? wtot[k2] : 0;
    int run = woff + x - acc;            // exclusive local start
    #pragma unroll
    for (int k = 0; k < 2; ++k) {
        int g = tid * K + k;
        if (k < K && g < G) {
            int cc = vals[k];
            cur[g] = run;                // own entries only: no race
            if (cc > 0)
                delta[g] = atomicAdd(&cursors[g], cc) - run;
            run += cc;
        }
    }
    __syncthreads();

    // LDS scatter, group-sorted (single dst/src/w pass; edges L3-hot)
    for (int i = beg + tid; i < end; i += 512) {
        int d = dst[i];
        unsigned int wb = __half_as_ushort(__float2half_rn(w[i]));
        unsigned int pk = ((unsigned int)src[i] << 15) | (wb & 0x7FFFu);
        int g = d >> SPAN_SH;
        int j = atomicAdd(&cur[g], 1);
        recs[j] = make_uint2(pk, (unsigned int)(d & (SPAN - 1)) |
                                 ((unsigned int)g << SPAN_SH));
    }
    __syncthreads();

    // linear coalesced drain
    for (int j = tid; j < n; j += 512) {
        uint2 r = recs[j];
        int g = (int)(r.y >> SPAN_SH);
        stream8[delta[g] + j] = make_uint2(r.x, r.y & (SPAN - 1u));
    }
}

// --- GF: fused per-group CSR + register gather + normalize (R6 proven) ----
__global__ __launch_bounds__(512) void gather_fused(
        const char* __restrict__ emb16b,      // row v at byte v*128
        const uint2* __restrict__ stream8,    // [E] {pk, dl}
        const int* __restrict__ offsets,      // [G+1]
        float* __restrict__ out, int N) {
    __shared__ uint2 lrec[TILE];              // 32 KB
    __shared__ unsigned int srt[TILE];        // 16 KB
    __shared__ int hcnt[SPAN];
    __shared__ int nstart[SPAN];
    __shared__ int cur[SPAN];
    __shared__ int wtot[2];

    const int g = blockIdx.x;
    const int tid = threadIdx.x;
    const int lane = tid & 63, wv = tid >> 6;
    const int base = offsets[g];
    const int endE = offsets[g + 1];
    const int crew = tid >> 4;                   // 0..31
    const int ql = tid & 15;
    const int sub = ql >> 3;                     // substream 0/1
    const int sl = ql & 7;                       // 16B segment of row
    const unsigned qlo = (unsigned)(sl << 4);

    float4 accA[4], accB[4];                  // dims sl*8+0..3 / +4..7
    #pragma unroll
    for (int ni = 0; ni < 4; ++ni) {
        accA[ni] = make_float4(0.f, 0.f, 0.f, 0.f);
        accB[ni] = make_float4(0.f, 0.f, 0.f, 0.f);
    }

    for (int tb = base; tb < endE; tb += TILE) {
        const int n = min(TILE, endE - tb);
        if (tid < SPAN) hcnt[tid] = 0;
        __syncthreads();
        for (int j = tid; j < n; j += 512) {
            uint2 r = stream8[tb + j];
            lrec[j] = r;
            atomicAdd(&hcnt[r.y], 1);
        }
        __syncthreads();
        int v = (tid < SPAN) ? hcnt[tid] : 0;
        int x = v;
        #pragma unroll
        for (int off = 1; off < 64; off <<= 1) {
            int t = __shfl_up(x, off, 64);
            if (lane >= off) x += t;
        }
        if (wv < 2 && lane == 63) wtot[wv] = x;
        __syncthreads();
        if (tid < SPAN) {
            int excl = x - v + ((wv == 1) ? wtot[0] : 0);
            nstart[tid] = excl;
            cur[tid] = excl;
        }
        __syncthreads();
        for (int j = tid; j < n; j += 512) {
            uint2 r = lrec[j];
            int slot = atomicAdd(&cur[r.y], 1);
            srt[slot] = r.x;
        }
        __syncthreads();
        #pragma unroll
        for (int ni = 0; ni < 4; ++ni) {
            int nd = crew + (ni << 5);
            int s = nstart[nd];
            int e = cur[nd];
            float4 aA = accA[ni];
            float4 aB = accB[ni];
            int k0 = s + sub;
            unsigned int pk0 = (k0 < e) ? srt[k0] : 0u;
            uint4 r0 = rowld(emb16b, pk0, qlo);
            for (int k = k0; k < e; k += 2) {
                int k1 = k + 2;
                unsigned int pk1 = (k1 < e) ? srt[k1] : 0u;
                uint4 r1 = rowld(emb16b, pk1, qlo);   // next in flight
                fma8(aA, aB, r0, h15_to_float(pk0 & 0x7FFFu));
                pk0 = pk1; r0 = r1;
            }
            accA[ni] = aA;
            accB[ni] = aB;
        }
        __syncthreads();
    }

    // merge substreams, normalize, write
    #pragma unroll
    for (int ni = 0; ni < 4; ++ni) {
        accA[ni].x += __shfl_xor(accA[ni].x, 8, 64);
        accA[ni].y += __shfl_xor(accA[ni].y, 8, 64);
        accA[ni].z += __shfl_xor(accA[ni].z, 8, 64);
        accA[ni].w += __shfl_xor(accA[ni].w, 8, 64);
        accB[ni].x += __shfl_xor(accB[ni].x, 8, 64);
        accB[ni].y += __shfl_xor(accB[ni].y, 8, 64);
        accB[ni].z += __shfl_xor(accB[ni].z, 8, 64);
        accB[ni].w += __shfl_xor(accB[ni].w, 8, 64);
        int node = g * SPAN + crew + (ni << 5);
        float4 aA = accA[ni];
        float4 aB = accB[ni];
        float ss = aA.x * aA.x + aA.y * aA.y + aA.z * aA.z + aA.w * aA.w
                 + aB.x * aB.x + aB.y * aB.y + aB.z * aB.z + aB.w * aB.w;
        ss += __shfl_xor(ss, 1, 64);
        ss += __shfl_xor(ss, 2, 64);
        ss += __shfl_xor(ss, 4, 64);
        float scale = 1.0f / fmaxf(sqrtf(ss), 1e-12f);
        if (node < N) {
            float4 a = sub ? aB : aA;
            float4 o = make_float4(a.x * scale, a.y * scale,
                                   a.z * scale, a.w * scale);
            *reinterpret_cast<float4*>(out + (size_t)node * EMB_D
                                       + (sl << 3) + (sub << 2)) = o;
        }
    }
}

// ===========================================================================
// Tier C: atomic scatter fallback.
// ===========================================================================
__global__ void lightgcn_scatter(const float* __restrict__ emb,
                                 const float* __restrict__ w,
                                 const int* __restrict__ src,
                                 const int* __restrict__ dst,
                                 float* __restrict__ h, int E) {
    long long t = (long long)blockIdx.x * blockDim.x + threadIdx.x;
    int e = (int)(t >> 4);
    int d = (int)(t & 15) << 2;
    if (e >= E) return;
    int s = src[e]; int v = dst[e]; float wt = w[e];
    const float4 m = *reinterpret_cast<const float4*>(emb + (size_t)s * EMB_D + d);
    float* o = h + (size_t)v * EMB_D + d;
    unsafeAtomicAdd(o + 0, m.x * wt);
    unsafeAtomicAdd(o + 1, m.y * wt);
    unsafeAtomicAdd(o + 2, m.z * wt);
    unsafeAtomicAdd(o + 3, m.w * wt);
}

__global__ void lightgcn_normalize(float* __restrict__ h, int N) {
    int row = blockIdx.x * (blockDim.x >> 6) + (threadIdx.x >> 6);
    int lane = threadIdx.x & 63;
    if (row >= N) return;
    float x = h[(size_t)row * EMB_D + lane];
    float ss = x * x;
    #pragma unroll
    for (int off = 32; off > 0; off >>= 1)
        ss += __shfl_xor(ss, off, 64);
    h[(size_t)row * EMB_D + lane] = x / fmaxf(sqrtf(ss), 1e-12f);
}

extern "C" void kernel_launch(void* const* d_in, const int* in_sizes, int n_in,
                              void* d_out, int out_size, void* d_ws, size_t ws_size,
                              hipStream_t stream) {
    const float* emb = (const float*)d_in[0];   // [N, 64] fp32
    const float* w   = (const float*)d_in[1];   // [E] fp32
    const int*   src = (const int*)d_in[2];     // [E] int32
    const int*   dst = (const int*)d_in[3];     // [E] int32
    float* out = (float*)d_out;

    const int N = in_sizes[0] / EMB_D;
    const int E = in_sizes[1];
    const int block = 256;
    const int G = (N + SPAN - 1) / SPAN;
    const int chunk = (E + NCHUNK2 - 1) / NCHUNK2;

    // ---- workspace: cntT[G*NCHUNK2] | hist[G] | offsets[G+1] | cursors[G]
    //      | pad | stream8[E] uint2 | pad | emb16  (~26.3 MB) ----
    size_t ints = (size_t)G * NCHUNK2 + 3 * (size_t)G + 1;
    size_t strOff = (ints * sizeof(int) + 15) & ~(size_t)15;
    size_t embOff = (strOff + (size_t)E * sizeof(uint2) + 15) & ~(size_t)15;
    size_t needed = embOff + (size_t)N * EMB_D * sizeof(__half);

    if (ws_size >= needed && G <= MAXG && chunk <= CHMAX &&
        E < (1 << 28) && N < (1 << 17)) {
        int* cntT    = (int*)d_ws;               // G*NCHUNK2
        int* hist    = cntT + (size_t)G * NCHUNK2;  // G
        int* offsets = hist + G;                 // G+1
        int* cursors = offsets + G + 1;          // G
        uint2* stream8 = (uint2*)((char*)d_ws + strOff);   // E
        uint2* emb16 = (uint2*)((char*)d_ws + embOff);

        int n4 = N * (EMB_D / 4);

        a1_cast_hist<<<CAST_BLOCKS + NCHUNK2, block, 0, stream>>>(
            (const float4*)emb, emb16, n4, dst, cntT, E, G, chunk);

        rowsum_kernel<<<G, 256, 0, stream>>>(cntT, hist, G);
        f2_scan_small<<<1, 1024, 0, stream>>>(hist, offsets, cursors, G);

        partition_res<<<NCHUNK2, 512, 0, stream>>>(src, dst, w, cntT, cursors,
                                                   stream8, E, G, chunk);

        gather_fused<<<G, 512, 0, stream>>>((const char*)emb16, stream8,
                                            offsets, out, N);
    } else {
        hipMemsetAsync(d_out, 0, (size_t)out_size * sizeof(float), stream);
        long long total = (long long)E * 16;
        int grid = (int)((total + block - 1) / block);
        lightgcn_scatter<<<grid, block, 0, stream>>>(emb, w, src, dst, out, E);
        int gridN = (N + 3) / 4;
        lightgcn_normalize<<<gridN, 256, 0, stream>>>(out, N);
    }
}